// Round 12
// baseline (240.349 us; speedup 1.0000x reference)
//
#include <hip/hip_runtime.h>
#include <hip/hip_bf16.h>

typedef __hip_bfloat16 bf16;
typedef __attribute__((ext_vector_type(8))) short short8;
typedef __attribute__((ext_vector_type(4))) float f32x4;
typedef __attribute__((ext_vector_type(16))) float f32x16;

#define B_    4
#define CIN   32
#define HH    256
#define WW    256
#define C1    384
#define NPIX  65536
#define CMID  128
#define COUT  32
#define PW    258
#define NCH   64

static __device__ __forceinline__ float u2f(unsigned short u) {
    unsigned int x = ((unsigned int)u) << 16;
    return __uint_as_float(x);
}
static __device__ __forceinline__ unsigned short f2u(float f) {
    bf16 h = __float2bfloat16(f);
    return __builtin_bit_cast(unsigned short, h);
}
static __device__ __forceinline__ unsigned int pk2(float lo, float hi) {
    return (unsigned int)f2u(lo) | ((unsigned int)f2u(hi) << 16);
}
static __device__ __forceinline__ void gload16(const void* src, void* dst) {
    __builtin_amdgcn_global_load_lds(
        (const __attribute__((address_space(1))) void*)src,
        (__attribute__((address_space(3))) void*)dst, 16, 0, 0);
}

// ---- w1(384,32,3,3) fp32 -> w1t[tap][cihi4][co384][8] bf16 ----
__global__ __launch_bounds__(256) void k_w1t(const float* __restrict__ w1, short* __restrict__ w1t) {
    const int tap = blockIdx.x;
    for (int i = threadIdx.x; i < 384 * 32; i += 256) {
        int co = i >> 5, cij = i & 31;
        w1t[((size_t)(tap * 4 + (cij >> 3)) * 384 + co) * 8 + (cij & 7)] =
            (short)f2u(w1[(size_t)i * 9 + tap]);
    }
}
// ---- w2(32,128,3,3) fp32 -> w2t[tap][cihi16][co32][8] bf16 ----
__global__ __launch_bounds__(256) void k_w2t(const float* __restrict__ w2, short* __restrict__ w2t) {
    const int tap = blockIdx.x;
    for (int i = threadIdx.x; i < 32 * 128; i += 256) {
        int co = i >> 7, cij = i & 127;
        w2t[((size_t)(tap * 16 + (cij >> 3)) * 32 + co) * 8 + (cij & 7)] =
            (short)f2u(w2[(size_t)i * 9 + tap]);
    }
}

// ---- x -> xt2[bl][row][cihi4][col PW][8ch] bf16, zero-padded ----
__global__ __launch_bounds__(256) void k_xt2(const float* __restrict__ x,
                                             unsigned short* __restrict__ xt2, int b0) {
    const int row = blockIdx.x, bl = blockIdx.y, b = b0 + bl;
    const int tx = threadIdx.x;
    unsigned short* rbase = xt2 + (size_t)(bl * PW + row) * 4 * PW * 8;
    const uint4 z = make_uint4(0u, 0u, 0u, 0u);
    if (row == 0 || row == PW - 1) {
        for (int i = tx; i < 4 * PW; i += 256) ((uint4*)rbase)[i] = z;
        return;
    }
    if (tx < 2) {
        int c = tx ? (PW - 1) : 0;
#pragma unroll
        for (int ch = 0; ch < 4; ch++)
            *(uint4*)(rbase + ((size_t)ch * PW + c) * 8) = z;
    }
    const int col = tx + 1;
    const size_t px = (size_t)(row - 1) * WW + tx;
    unsigned int pk[16];
#pragma unroll
    for (int c2 = 0; c2 < 16; c2++) {
        float v0 = x[((size_t)b * CIN + 2 * c2) * NPIX + px];
        float v1 = x[((size_t)b * CIN + 2 * c2 + 1) * NPIX + px];
        pk[c2] = pk2(v0, v1);
    }
#pragma unroll
    for (int ch = 0; ch < 4; ch++)
        *(uint4*)(rbase + ((size_t)ch * PW + col) * 8) =
            make_uint4(pk[ch * 4], pk[ch * 4 + 1], pk[ch * 4 + 2], pk[ch * 4 + 3]);
}

// ---- conv1: ONE cog per block (6x finer grid); XCD-chunked swizzle; 2 barriers/block ----
// grid: 12*256*nb blocks. LDS: xs 25344 + ou 17408 = 42752 B -> 3 blocks/CU
__global__ __launch_bounds__(256, 3) void k_conv1(
    const unsigned short* __restrict__ xt2, const short* __restrict__ w1t,
    const float* __restrict__ b1, unsigned short* __restrict__ qkv,
    unsigned short* __restrict__ vt, int nb)
{
    const int nblk = 3072 * nb;
    const int m = (blockIdx.x & 7) * (nblk >> 3) + (blockIdx.x >> 3);
    const int cog = m % 6;                 // innermost: 6 cogs share one xs patch (same XCD)
    const int rem = m / 6;
    const int chunk = rem & 1;
    const int y   = (rem >> 1) & 255;
    const int bl  = rem >> 9;
    const int px0 = chunk * 128;
    const int co0 = cog * 64;
    const int tx  = threadIdx.x;
    const int wv  = tx >> 6, l = tx & 63;
    const int lhi = l >> 4, llo = l & 15;

    __shared__ short xs[12 * 132 * 8];
    __shared__ union { short os[64][136]; short ost[128][66]; } ou;

    // stage x patch: 12 (row,cihi) segs of 130 cols
#pragma unroll
    for (int i = 0; i < 3; i++) {
        int p = wv * 3 + i;
        int r = p >> 2, ch = p & 3;
        const char* src = (const char*)xt2 +
            (((size_t)(bl * PW) + y + r) * 4 + ch) * (PW * 16) + (size_t)px0 * 16 + (size_t)l * 16;
        char* dst = (char*)xs + p * 2112;
        gload16(src, dst);
        gload16(src + 1024, dst + 1024);
        if (l < 2) gload16(src + 2048, dst + 2048);
    }

    const short* wbase = w1t + ((size_t)lhi * 384 + llo) * 8;
    // A-frag prefetch from L2 (independent of LDS barrier)
    short8 a[4], an[4];
#pragma unroll
    for (int mc = 0; mc < 4; mc++)
        an[mc] = *(const short8*)(wbase + ((size_t)co0 + mc * 16) * 8);

    float bias[4][4];
#pragma unroll
    for (int mc = 0; mc < 4; mc++)
#pragma unroll
        for (int r = 0; r < 4; r++)
            bias[mc][r] = b1[co0 + mc * 16 + lhi * 4 + r];

    __syncthreads();   // xs ready

    f32x4 acc[2][4];
#pragma unroll
    for (int t = 0; t < 2; t++)
#pragma unroll
        for (int mc = 0; mc < 4; mc++) acc[t][mc] = (f32x4){0.f, 0.f, 0.f, 0.f};

#pragma unroll
    for (int tap = 0; tap < 9; tap++) {
        const int dy = tap / 3, dx = tap % 3;
#pragma unroll
        for (int mc = 0; mc < 4; mc++) a[mc] = an[mc];
        if (tap < 8) {
#pragma unroll
            for (int mc = 0; mc < 4; mc++)
                an[mc] = *(const short8*)(wbase +
                    ((size_t)(tap + 1) * 4 * 384 + co0 + mc * 16) * 8);
        }
#pragma unroll
        for (int t = 0; t < 2; t++) {
            short8 bfr = *(const short8*)&xs[(((dy * 4 + lhi) * 132) + (wv * 32 + t * 16 + llo + dx)) * 8];
#pragma unroll
            for (int mc = 0; mc < 4; mc++)
                acc[t][mc] = __builtin_amdgcn_mfma_f32_16x16x32_bf16(a[mc], bfr, acc[t][mc], 0, 0, 0);
        }
    }

    if (cog < 4) {     // q,k: channel-major staging
#pragma unroll
        for (int t = 0; t < 2; t++)
#pragma unroll
            for (int mc = 0; mc < 4; mc++)
#pragma unroll
                for (int r = 0; r < 4; r++)
                    ou.os[mc * 16 + lhi * 4 + r][wv * 32 + t * 16 + llo] =
                        (short)f2u(acc[t][mc][r] + bias[mc][r]);
    } else {           // v: transposed [px][ch] staging
#pragma unroll
        for (int t = 0; t < 2; t++)
#pragma unroll
            for (int mc = 0; mc < 4; mc++)
#pragma unroll
                for (int r = 0; r < 4; r++)
                    ou.ost[wv * 32 + t * 16 + llo][mc * 16 + lhi * 4 + r] =
                        (short)f2u(acc[t][mc][r] + bias[mc][r]);
    }
    __syncthreads();   // ou visible

    if (cog < 4) {
        // 16 lanes x 16B = 256B contiguous per channel per instruction
#pragma unroll
        for (int p = 0; p < 4; p++) {
            int chl = p * 16 + (tx >> 4);
            int c = co0 + chl;
            int comp = c >> 7, chn = c & 127;
            uint4 v = *(const uint4*)&ou.os[chl][(tx & 15) * 8];
            *(uint4*)(qkv + ((size_t)(comp * nb + bl) * CMID + chn) * NPIX
                      + y * WW + px0 + (tx & 15) * 8) = v;
        }
    } else {
        // linear copy: each wave instruction writes 1KB contiguous to vt
        unsigned short* dst = vt + ((size_t)(bl * 2 + (cog - 4)) * NPIX
                                    + y * WW + px0) * 64;
#pragma unroll
        for (int i = 0; i < 4; i++) {
            int u = i * 256 + tx;
            int px = u >> 3, q = u & 7;
            uint4 v = *(const uint4*)&ou.ost[px][q * 8];
            *(uint4*)(dst + (size_t)u * 8) = v;
        }
    }
}

// ---- weights GEMM partials ----
__global__ __launch_bounds__(256) void k_weights(
    const unsigned short* __restrict__ qkv, float* __restrict__ pw,
    float* __restrict__ ps, int nb)
{
    const int c  = blockIdx.x;
    const int bh = blockIdx.y;
    const int bl = bh >> 2, h = bh & 3;
    const int tx = threadIdx.x;
    const int wv = tx >> 6, l = tx & 63;
    const int col = l & 31;
    const int kg  = l >> 5;

    const unsigned short* qb = qkv + ((size_t)bl * CMID + h * 32 + col) * NPIX;
    const unsigned short* kb = qkv + ((size_t)(nb + bl) * CMID + h * 32 + col) * NPIX;
    const int n0 = c * 1024 + wv * 256 + kg * 8;

    f32x16 acc;
#pragma unroll
    for (int r = 0; r < 16; r++) acc[r] = 0.f;
    float se = 0.f;

#pragma unroll 4
    for (int s = 0; s < 16; s++) {
        const int n = n0 + s * 16;
        short8 qf = *(const short8*)(qb + n);
        short8 kf = *(const short8*)(kb + n);
        float ef[8];
#pragma unroll
        for (int j = 0; j < 8; j++) {
            ef[j] = __expf(u2f((unsigned short)kf[j]));
            se += ef[j];
        }
        short8 pf;
#pragma unroll
        for (int j = 0; j < 8; j++) pf[j] = (short)f2u(ef[j]);
        acc = __builtin_amdgcn_mfma_f32_32x32x16_bf16(qf, pf, acc, 0, 0, 0);
    }

    __shared__ float red[4][1024];
    __shared__ float sred[4][64];
#pragma unroll
    for (int r = 0; r < 16; r++) {
        int row = (r & 3) + 8 * (r >> 2) + 4 * kg;
        red[wv][row * 32 + col] = acc[r];
    }
    sred[wv][l] = se;
    __syncthreads();

    float* pwp = pw + ((size_t)bh * NCH + c) * 1024;
#pragma unroll
    for (int j = 0; j < 4; j++) {
        int i = tx + 256 * j;
        pwp[i] = red[0][i] + red[1][i] + red[2][i] + red[3][i];
    }
    if (tx < 32) {
        float s = 0.f;
#pragma unroll
        for (int w = 0; w < 4; w++) s += sred[w][tx] + sred[w][tx + 32];
        ps[((size_t)bh * NCH + c) * 32 + tx] = s;
    }
}

// ---- reduce partials ----
__global__ __launch_bounds__(256) void k_wred(
    const float* __restrict__ pw, const float* __restrict__ ps,
    float* __restrict__ wts, int b0)
{
    const int bh = blockIdx.x;
    const int jq = blockIdx.y;
    const int tx = threadIdx.x;
    __shared__ float rinvs[32];
    if (tx < 32) {
        float s = 0.f;
        for (int c = 0; c < NCH; c++) s += ps[((size_t)bh * NCH + c) * 32 + tx];
        rinvs[tx] = 1.f / s;
    }
    __syncthreads();
    const int i = jq * 256 + tx;
    const float* pwp = pw + (size_t)bh * NCH * 1024;
    float s = 0.f;
    for (int c = 0; c < NCH; c++) s += pwp[c * 1024 + i];
    wts[(size_t)(b0 * 4 + bh) * 1024 + i] = s * rinvs[i & 31];
}

// ---- zero at2 borders: layout [bl][row][chgrp16][col PW][8] ----
__global__ __launch_bounds__(256) void k_bord(unsigned short* __restrict__ at2) {
    const int row = blockIdx.x, bl = blockIdx.y, tx = threadIdx.x;
    unsigned short* base = at2 + (size_t)(bl * PW + row) * 16 * PW * 8;
    const uint4 z = make_uint4(0u, 0u, 0u, 0u);
    if (row == 0 || row == PW - 1) {
        for (int i = tx; i < 16 * PW; i += 256) ((uint4*)base)[i] = z;
    } else if (tx < 32) {
        int g = tx >> 1, c = (tx & 1) * (PW - 1);
        *(uint4*)(base + ((size_t)g * PW + c) * 8) = z;
    }
}

// ---- attnout via MFMA ----
__global__ __launch_bounds__(256, 4) void k_attnout(
    const unsigned short* __restrict__ vt, const float* __restrict__ wts,
    unsigned short* __restrict__ at2, int b0, int nb)
{
    const int bl = blockIdx.y, b = b0 + bl;
    const int tx = threadIdx.x, wv = tx >> 6, l = tx & 63;
    const int e = l & 31, kg = l >> 5;
    const int pxb = blockIdx.x * 256 + wv * 64;

    __shared__ float osa[4][32][34];

    short8 Bf[4][2];
    const float* Wb = wts + (size_t)b * 4096;
#pragma unroll
    for (int h = 0; h < 4; h++)
#pragma unroll
        for (int kk = 0; kk < 2; kk++) {
            short8 v;
#pragma unroll
            for (int j = 0; j < 8; j++) {
                int d = kk * 16 + kg * 8 + j;
                v[j] = (short)f2u(Wb[h * 1024 + d * 32 + e]);
            }
            Bf[h][kk] = v;
        }

    const unsigned short* vbase = vt + (size_t)bl * 2 * NPIX * 64;

#pragma unroll
    for (int t = 0; t < 2; t++) {
        const int px0 = pxb + t * 32;
#pragma unroll
        for (int h = 0; h < 4; h++) {
            const unsigned short* vp = vbase + (size_t)(h >> 1) * NPIX * 64
                                     + (size_t)(px0 + e) * 64 + (h & 1) * 32 + kg * 8;
            short8 a0 = *(const short8*)vp;
            short8 a1 = *(const short8*)(vp + 16);
            f32x16 acc;
#pragma unroll
            for (int r = 0; r < 16; r++) acc[r] = 0.f;
            acc = __builtin_amdgcn_mfma_f32_32x32x16_bf16(a0, Bf[h][0], acc, 0, 0, 0);
            acc = __builtin_amdgcn_mfma_f32_32x32x16_bf16(a1, Bf[h][1], acc, 0, 0, 0);

#pragma unroll
            for (int r = 0; r < 16; r++) {
                int pxl = (r & 3) + 8 * (r >> 2) + 4 * kg;
                osa[wv][e][pxl] = acc[r];
            }
#pragma unroll
            for (int it = 0; it < 2; it++) {
                int u = it * 64 + l;
                int eg = u >> 5, px = u & 31;
                short8 o;
#pragma unroll
                for (int j = 0; j < 8; j++) o[j] = (short)f2u(osa[wv][eg * 8 + j][px]);
                int gp = px0 + px;
                int prow = gp >> 8, pcol = gp & 255;
                *(short8*)(at2 + (((size_t)(bl * PW) + 1 + prow) * 16 + h * 4 + eg) * (PW * 8)
                           + (size_t)(1 + pcol) * 8) = o;
            }
        }
    }
}

// ---- conv2: implicit GEMM from subtiled at2 ----
__global__ __launch_bounds__(256, 3) void k_conv2(
    const unsigned short* __restrict__ at2, const short* __restrict__ w2t,
    const float* __restrict__ b2, float* __restrict__ out, int b0, int nb)
{
    const int bid = blockIdx.x;
    const int chunk = bid & 1;
    const int y   = (bid >> 1) & 255;
    const int bl  = bid >> 9;
    const int px0 = chunk * 128;
    const int bb  = b0 + bl;
    const int tx  = threadIdx.x;
    const int wv  = tx >> 6, l = tx & 63;
    const int lhi = l >> 4, llo = l & 15;

    __shared__ short xs[12 * 132 * 8];
    __shared__ float osf[32][132];

    float bias[2][4];
#pragma unroll
    for (int m = 0; m < 2; m++)
#pragma unroll
        for (int r = 0; r < 4; r++)
            bias[m][r] = b2[m * 16 + lhi * 4 + r];

    f32x4 acc[2][2];
#pragma unroll
    for (int t = 0; t < 2; t++)
#pragma unroll
        for (int m = 0; m < 2; m++) acc[t][m] = (f32x4){0.f, 0.f, 0.f, 0.f};

    for (int cc = 0; cc < 4; cc++) {
        __syncthreads();
#pragma unroll
        for (int i = 0; i < 3; i++) {
            int p = wv * 3 + i;
            int r = p >> 2, ch = p & 3;
            const char* src = (const char*)at2 +
                (((size_t)(bl * PW) + y + r) * 16 + cc * 4 + ch) * (PW * 16)
                + (size_t)px0 * 16 + (size_t)l * 16;
            char* dst = (char*)xs + p * 2112;
            gload16(src, dst);
            gload16(src + 1024, dst + 1024);
            if (l < 2) gload16(src + 2048, dst + 2048);
        }
        __syncthreads();

        short8 a[2], an[2];
#pragma unroll
        for (int m = 0; m < 2; m++)
            an[m] = *(const short8*)(w2t + ((size_t)(cc * 4 + lhi) * 32 + m * 16 + llo) * 8);
#pragma unroll
        for (int tap = 0; tap < 9; tap++) {
            const int dy = tap / 3, dx = tap % 3;
#pragma unroll
            for (int m = 0; m < 2; m++) a[m] = an[m];
            if (tap < 8) {
#pragma unroll
                for (int m = 0; m < 2; m++)
                    an[m] = *(const short8*)(w2t +
                        ((size_t)((tap + 1) * 16 + cc * 4 + lhi) * 32 + m * 16 + llo) * 8);
            }
#pragma unroll
            for (int t = 0; t < 2; t++) {
                short8 bfr = *(const short8*)&xs[(((dy * 4 + lhi) * 132) + (wv * 32 + t * 16 + llo + dx)) * 8];
#pragma unroll
                for (int m = 0; m < 2; m++)
                    acc[t][m] = __builtin_amdgcn_mfma_f32_16x16x32_bf16(a[m], bfr, acc[t][m], 0, 0, 0);
            }
        }
    }

#pragma unroll
    for (int t = 0; t < 2; t++)
#pragma unroll
        for (int m = 0; m < 2; m++)
#pragma unroll
            for (int r = 0; r < 4; r++)
                osf[m * 16 + lhi * 4 + r][wv * 32 + t * 16 + llo] = acc[t][m][r] + bias[m][r];
    __syncthreads();
#pragma unroll
    for (int p = 0; p < 4; p++) {
        int chl = p * 8 + (tx >> 5);
        float4 v = *(const float4*)&osf[chl][(tx & 31) * 4];
        *(float4*)(out + ((size_t)bb * COUT + chl) * NPIX + y * WW + px0 + (tx & 31) * 4) = v;
    }
}

extern "C" void kernel_launch(void* const* d_in, const int* in_sizes, int n_in,
                              void* d_out, int out_size, void* d_ws, size_t ws_size,
                              hipStream_t stream) {
    const float* x  = (const float*)d_in[0];
    const float* w1 = (const float*)d_in[1];
    const float* b1 = (const float*)d_in[2];
    const float* w2 = (const float*)d_in[3];
    const float* b2 = (const float*)d_in[4];
    float* out = (float*)d_out;

    char* ws = (char*)d_ws;
    float* wts  = (float*)(ws + 4096);
    short* w1t  = (short*)(ws + 69632);
    short* w2t  = (short*)(ws + 290816);
    const size_t OFF_XT = 1048576;

    int nb = 4;
    {
        size_t xt_sz = (size_t)nb * PW * 4 * PW * 16;
        size_t total = OFF_XT + xt_sz + (size_t)2 * nb * CMID * NPIX * 2
                     + (size_t)nb * 2 * NPIX * 64 * 2;
        if (ws_size < total) nb = 1;
    }
    const size_t xt_sz   = (size_t)nb * PW * 4 * PW * 16;
    const size_t qkv_off = OFF_XT + xt_sz;
    const size_t vt_off  = qkv_off + (size_t)2 * nb * CMID * NPIX * 2;

    unsigned short* xt2 = (unsigned short*)(ws + OFF_XT);
    unsigned short* qkv = (unsigned short*)(ws + qkv_off);
    unsigned short* vt  = (unsigned short*)(ws + vt_off);
    unsigned short* at2 = (unsigned short*)(ws + qkv_off);
    float* pw = (float*)(ws + OFF_XT);
    float* ps = (float*)(ws + OFF_XT + (size_t)nb * 4 * NCH * 1024 * 4);

    k_w1t<<<dim3(9), 256, 0, stream>>>(w1, w1t);
    k_w2t<<<dim3(9), 256, 0, stream>>>(w2, w2t);

    for (int b0 = 0; b0 < B_; b0 += nb) {
        k_xt2    <<<dim3(PW, nb),        256, 0, stream>>>(x, xt2, b0);
        k_conv1  <<<dim3(12 * HH * nb),  256, 0, stream>>>(xt2, w1t, b1, qkv, vt, nb);
        k_weights<<<dim3(NCH, nb * 4),   256, 0, stream>>>(qkv, pw, ps, nb);
        k_wred   <<<dim3(nb * 4, 4),     256, 0, stream>>>(pw, ps, wts, b0);
        k_bord   <<<dim3(PW, nb),        256, 0, stream>>>(at2);
        k_attnout<<<dim3(NPIX / 256, nb),256, 0, stream>>>(vt, wts, at2, b0, nb);
        k_conv2  <<<dim3(2 * HH * nb),   256, 0, stream>>>(at2, w2t, b2, out, b0, nb);
    }
}

// Round 13
// 222.772 us; speedup vs baseline: 1.0789x; 1.0789x over previous
//
#include <hip/hip_runtime.h>
#include <hip/hip_bf16.h>

typedef __hip_bfloat16 bf16;
typedef __attribute__((ext_vector_type(8))) short short8;
typedef __attribute__((ext_vector_type(4))) float f32x4;
typedef __attribute__((ext_vector_type(16))) float f32x16;

#define B_    4
#define CIN   32
#define HH    256
#define WW    256
#define C1    384
#define NPIX  65536
#define CMID  128
#define COUT  32
#define PW    258

static __device__ __forceinline__ float u2f(unsigned short u) {
    unsigned int x = ((unsigned int)u) << 16;
    return __uint_as_float(x);
}
static __device__ __forceinline__ unsigned short f2u(float f) {
    bf16 h = __float2bfloat16(f);
    return __builtin_bit_cast(unsigned short, h);
}
static __device__ __forceinline__ unsigned int pk2(float lo, float hi) {
    return (unsigned int)f2u(lo) | ((unsigned int)f2u(hi) << 16);
}
static __device__ __forceinline__ void gload16(const void* src, void* dst) {
    __builtin_amdgcn_global_load_lds(
        (const __attribute__((address_space(1))) void*)src,
        (__attribute__((address_space(3))) void*)dst, 16, 0, 0);
}

// ---- w1(384,32,3,3) fp32 -> w1t[tap][cihi4][co384][8] bf16 ----
__global__ __launch_bounds__(256) void k_w1t(const float* __restrict__ w1, short* __restrict__ w1t) {
    const int tap = blockIdx.x;
    for (int i = threadIdx.x; i < 384 * 32; i += 256) {
        int co = i >> 5, cij = i & 31;
        w1t[((size_t)(tap * 4 + (cij >> 3)) * 384 + co) * 8 + (cij & 7)] =
            (short)f2u(w1[(size_t)i * 9 + tap]);
    }
}
// ---- w2(32,128,3,3) fp32 -> w2t[tap][cihi16][co32][8] bf16 ----
__global__ __launch_bounds__(256) void k_w2t(const float* __restrict__ w2, short* __restrict__ w2t) {
    const int tap = blockIdx.x;
    for (int i = threadIdx.x; i < 32 * 128; i += 256) {
        int co = i >> 7, cij = i & 127;
        w2t[((size_t)(tap * 16 + (cij >> 3)) * 32 + co) * 8 + (cij & 7)] =
            (short)f2u(w2[(size_t)i * 9 + tap]);
    }
}

// ---- x -> xt2[bl][row][cihi4][col PW][8ch] bf16, zero-padded ----
__global__ __launch_bounds__(256) void k_xt2(const float* __restrict__ x,
                                             unsigned short* __restrict__ xt2, int b0) {
    const int row = blockIdx.x, bl = blockIdx.y, b = b0 + bl;
    const int tx = threadIdx.x;
    unsigned short* rbase = xt2 + (size_t)(bl * PW + row) * 4 * PW * 8;
    const uint4 z = make_uint4(0u, 0u, 0u, 0u);
    if (row == 0 || row == PW - 1) {
        for (int i = tx; i < 4 * PW; i += 256) ((uint4*)rbase)[i] = z;
        return;
    }
    if (tx < 2) {
        int c = tx ? (PW - 1) : 0;
#pragma unroll
        for (int ch = 0; ch < 4; ch++)
            *(uint4*)(rbase + ((size_t)ch * PW + c) * 8) = z;
    }
    const int col = tx + 1;
    const size_t px = (size_t)(row - 1) * WW + tx;
    unsigned int pk[16];
#pragma unroll
    for (int c2 = 0; c2 < 16; c2++) {
        float v0 = x[((size_t)b * CIN + 2 * c2) * NPIX + px];
        float v1 = x[((size_t)b * CIN + 2 * c2 + 1) * NPIX + px];
        pk[c2] = pk2(v0, v1);
    }
#pragma unroll
    for (int ch = 0; ch < 4; ch++)
        *(uint4*)(rbase + ((size_t)ch * PW + col) * 8) =
            make_uint4(pk[ch * 4], pk[ch * 4 + 1], pk[ch * 4 + 2], pk[ch * 4 + 3]);
}

// ---- conv1 FUSED: qkv conv + attention-weights GEMM; q,k never leave the block ----
// grid 512*nb (XCD-swizzled). Per block: 6 cogs; waves own heads (wave w = head w).
// Outputs: vt (NHWC v), pw (per-chunk W partials), ps (per-chunk expsums).
__global__ __launch_bounds__(256, 3) void k_conv1(
    const unsigned short* __restrict__ xt2, const short* __restrict__ w1t,
    const float* __restrict__ b1, unsigned short* __restrict__ vt,
    float* __restrict__ pw, float* __restrict__ ps, int nb)
{
    const int nblk = 512 * nb;
    const int m = ((int)blockIdx.x & 7) * (nblk >> 3) + ((int)blockIdx.x >> 3);
    const int chunk = m & 1;
    const int y   = (m >> 1) & 255;
    const int bl  = m >> 9;
    const int px0 = chunk * 128;
    const int cid = bl * 512 + y * 2 + chunk;
    const int tx  = threadIdx.x;
    const int wv  = tx >> 6, l = tx & 63;
    const int lhi = l >> 4, llo = l & 15;

    __shared__ short xs[12 * 132 * 8];
    __shared__ union {
        short os[64][136];
        short ost[128][66];
        float osw[4][32][32];
    } ou;

    // stage x patch
#pragma unroll
    for (int i = 0; i < 3; i++) {
        int p = wv * 3 + i;
        int r = p >> 2, ch = p & 3;
        const char* src = (const char*)xt2 +
            (((size_t)(bl * PW) + y + r) * 4 + ch) * (PW * 16) + (size_t)px0 * 16 + (size_t)l * 16;
        char* dst = (char*)xs + p * 2112;
        gload16(src, dst);
        gload16(src + 1024, dst + 1024);
        if (l < 2) gload16(src + 2048, dst + 2048);
    }
    __syncthreads();

    const short* wbase = w1t + ((size_t)lhi * 384 + llo) * 8;

    short8 qa[2][4];          // q A-frags [dtile][kstep], persist q-cog -> k-cog
    f32x4 wacc[2][2];         // weights accum [dtile][etile]
#pragma unroll
    for (int dt = 0; dt < 2; dt++)
#pragma unroll
        for (int et = 0; et < 2; et++) wacc[dt][et] = (f32x4){0.f, 0.f, 0.f, 0.f};
    float se0 = 0.f, se1 = 0.f;

#pragma unroll
    for (int cog = 0; cog < 6; cog++) {
        const int co0 = cog * 64;

        f32x4 acc[2][4];
#pragma unroll
        for (int t = 0; t < 2; t++)
#pragma unroll
            for (int mc = 0; mc < 4; mc++) acc[t][mc] = (f32x4){0.f, 0.f, 0.f, 0.f};

        short8 a[4], an[4];
#pragma unroll
        for (int mc = 0; mc < 4; mc++)
            an[mc] = *(const short8*)(wbase + ((size_t)co0 + mc * 16) * 8);
#pragma unroll
        for (int tap = 0; tap < 9; tap++) {
            const int dy = tap / 3, dx = tap % 3;
#pragma unroll
            for (int mc = 0; mc < 4; mc++) a[mc] = an[mc];
            if (tap < 8) {
#pragma unroll
                for (int mc = 0; mc < 4; mc++)
                    an[mc] = *(const short8*)(wbase +
                        ((size_t)(tap + 1) * 4 * 384 + co0 + mc * 16) * 8);
            }
#pragma unroll
            for (int t = 0; t < 2; t++) {
                short8 bfr = *(const short8*)&xs[(((dy * 4 + lhi) * 132) + (wv * 32 + t * 16 + llo + dx)) * 8];
#pragma unroll
                for (int mc = 0; mc < 4; mc++)
                    acc[t][mc] = __builtin_amdgcn_mfma_f32_16x16x32_bf16(a[mc], bfr, acc[t][mc], 0, 0, 0);
            }
        }

        float bias[4][4];
#pragma unroll
        for (int mc = 0; mc < 4; mc++)
#pragma unroll
            for (int r = 0; r < 4; r++)
                bias[mc][r] = b1[co0 + mc * 16 + lhi * 4 + r];

        __syncthreads();   // previous ou readers done

        if (cog < 4) {     // q,k: channel-major staging [ch64][px128]
#pragma unroll
            for (int t = 0; t < 2; t++)
#pragma unroll
                for (int mc = 0; mc < 4; mc++)
#pragma unroll
                    for (int r = 0; r < 4; r++)
                        ou.os[mc * 16 + lhi * 4 + r][wv * 32 + t * 16 + llo] =
                            (short)f2u(acc[t][mc][r] + bias[mc][r]);
        } else {           // v: transposed [px][ch] staging
#pragma unroll
            for (int t = 0; t < 2; t++)
#pragma unroll
                for (int mc = 0; mc < 4; mc++)
#pragma unroll
                    for (int r = 0; r < 4; r++)
                        ou.ost[wv * 32 + t * 16 + llo][mc * 16 + lhi * 4 + r] =
                            (short)f2u(acc[t][mc][r] + bias[mc][r]);
        }
        __syncthreads();   // ou visible

        if (cog < 2) {
            // q cog: owning waves load A-frags (q[d][n] matches MFMA A layout)
            if ((wv >> 1) == cog) {
                const int chb = (wv & 1) * 32;
#pragma unroll
                for (int dt = 0; dt < 2; dt++)
#pragma unroll
                    for (int ks = 0; ks < 4; ks++)
                        qa[dt][ks] = *(const short8*)&ou.os[chb + dt * 16 + llo][ks * 32 + lhi * 8];
            }
        } else if (cog < 4) {
            // k cog: owning waves build exp(k) B-frags + expsum, accumulate weights MFMA
            if ((wv >> 1) == cog - 2) {
                const int chb = (wv & 1) * 32;
#pragma unroll
                for (int et = 0; et < 2; et++)
#pragma unroll
                    for (int ks = 0; ks < 4; ks++) {
                        short8 kf = *(const short8*)&ou.os[chb + et * 16 + llo][ks * 32 + lhi * 8];
                        short8 pf;
#pragma unroll
                        for (int j = 0; j < 8; j++) {
                            float ef = __expf(u2f((unsigned short)kf[j]));
                            if (et == 0) se0 += ef; else se1 += ef;
                            pf[j] = (short)f2u(ef);
                        }
#pragma unroll
                        for (int dt = 0; dt < 2; dt++)
                            wacc[dt][et] = __builtin_amdgcn_mfma_f32_16x16x32_bf16(
                                qa[dt][ks], pf, wacc[dt][et], 0, 0, 0);
                    }
            }
        } else {
            // v: linear 1KB-per-instruction store to vt
            unsigned short* dst = vt + ((size_t)(bl * 2 + (cog - 4)) * NPIX
                                        + y * WW + px0) * 64;
#pragma unroll
            for (int i = 0; i < 4; i++) {
                int u = i * 256 + tx;
                int px = u >> 3, q = u & 7;
                uint4 v = *(const uint4*)&ou.ost[px][q * 8];
                *(uint4*)(dst + (size_t)u * 8) = v;
            }
        }
    }

    // expsum reduce across the 4 k-groups (lanes sharing l&15)
    se0 += __shfl_xor(se0, 16); se0 += __shfl_xor(se0, 32);
    se1 += __shfl_xor(se1, 16); se1 += __shfl_xor(se1, 32);
    if (l < 16) {
        ps[(size_t)cid * 128 + wv * 32 + llo]      = se0;
        ps[(size_t)cid * 128 + wv * 32 + 16 + llo] = se1;
    }

    __syncthreads();   // cog5 ost readers done
    // stage W partials: wave wv = head wv, D layout row=(l>>4)*4+r, col=l&15
#pragma unroll
    for (int dt = 0; dt < 2; dt++)
#pragma unroll
        for (int et = 0; et < 2; et++)
#pragma unroll
            for (int r = 0; r < 4; r++)
                ou.osw[wv][dt * 16 + lhi * 4 + r][et * 16 + llo] = wacc[dt][et][r];
    __syncthreads();

    {
        float* pwp = pw + (size_t)cid * 4096;
        const float* osf = (const float*)&ou;
#pragma unroll
        for (int p = 0; p < 4; p++)
            *(float4*)(pwp + p * 1024 + tx * 4) = *(const float4*)(osf + p * 1024 + tx * 4);
    }
}

// ---- reduce partials over 512 chunks: wts[bh][d*32+e] = sum_c pw / sum_c ps[e] ----
__global__ __launch_bounds__(256) void k_wred(
    const float* __restrict__ pw, const float* __restrict__ ps,
    float* __restrict__ wts, int b0)
{
    const int bh = blockIdx.x;          // bl*4+h
    const int jq = blockIdx.y;
    const int bl = bh >> 2, h = bh & 3;
    const int tx = threadIdx.x;
    __shared__ float rinvs[32];
    if (tx < 32) {
        float s = 0.f;
        const float* pp = ps + (size_t)bl * 512 * 128 + h * 32 + tx;
        for (int c = 0; c < 512; c++) s += pp[(size_t)c * 128];
        rinvs[tx] = 1.f / s;
    }
    __syncthreads();
    const int i = jq * 256 + tx;
    const float* pwp = pw + (size_t)bl * 512 * 4096 + h * 1024 + i;
    float s = 0.f;
    for (int c = 0; c < 512; c++) s += pwp[(size_t)c * 4096];
    wts[(size_t)(b0 * 4 + bh) * 1024 + i] = s * rinvs[i & 31];
}

// ---- zero at2 borders: layout [bl][row][chgrp16][col PW][8] ----
__global__ __launch_bounds__(256) void k_bord(unsigned short* __restrict__ at2) {
    const int row = blockIdx.x, bl = blockIdx.y, tx = threadIdx.x;
    unsigned short* base = at2 + (size_t)(bl * PW + row) * 16 * PW * 8;
    const uint4 z = make_uint4(0u, 0u, 0u, 0u);
    if (row == 0 || row == PW - 1) {
        for (int i = tx; i < 16 * PW; i += 256) ((uint4*)base)[i] = z;
    } else if (tx < 32) {
        int g = tx >> 1, c = (tx & 1) * (PW - 1);
        *(uint4*)(base + ((size_t)g * PW + c) * 8) = z;
    }
}

// ---- attnout via MFMA ----
__global__ __launch_bounds__(256, 4) void k_attnout(
    const unsigned short* __restrict__ vt, const float* __restrict__ wts,
    unsigned short* __restrict__ at2, int b0, int nb)
{
    const int bl = blockIdx.y, b = b0 + bl;
    const int tx = threadIdx.x, wv = tx >> 6, l = tx & 63;
    const int e = l & 31, kg = l >> 5;
    const int pxb = blockIdx.x * 256 + wv * 64;

    __shared__ float osa[4][32][34];

    short8 Bf[4][2];
    const float* Wb = wts + (size_t)b * 4096;
#pragma unroll
    for (int h = 0; h < 4; h++)
#pragma unroll
        for (int kk = 0; kk < 2; kk++) {
            short8 v;
#pragma unroll
            for (int j = 0; j < 8; j++) {
                int d = kk * 16 + kg * 8 + j;
                v[j] = (short)f2u(Wb[h * 1024 + d * 32 + e]);
            }
            Bf[h][kk] = v;
        }

    const unsigned short* vbase = vt + (size_t)bl * 2 * NPIX * 64;

#pragma unroll
    for (int t = 0; t < 2; t++) {
        const int px0 = pxb + t * 32;
#pragma unroll
        for (int h = 0; h < 4; h++) {
            const unsigned short* vp = vbase + (size_t)(h >> 1) * NPIX * 64
                                     + (size_t)(px0 + e) * 64 + (h & 1) * 32 + kg * 8;
            short8 a0 = *(const short8*)vp;
            short8 a1 = *(const short8*)(vp + 16);
            f32x16 acc;
#pragma unroll
            for (int r = 0; r < 16; r++) acc[r] = 0.f;
            acc = __builtin_amdgcn_mfma_f32_32x32x16_bf16(a0, Bf[h][0], acc, 0, 0, 0);
            acc = __builtin_amdgcn_mfma_f32_32x32x16_bf16(a1, Bf[h][1], acc, 0, 0, 0);

#pragma unroll
            for (int r = 0; r < 16; r++) {
                int pxl = (r & 3) + 8 * (r >> 2) + 4 * kg;
                osa[wv][e][pxl] = acc[r];
            }
#pragma unroll
            for (int it = 0; it < 2; it++) {
                int u = it * 64 + l;
                int eg = u >> 5, px = u & 31;
                short8 o;
#pragma unroll
                for (int j = 0; j < 8; j++) o[j] = (short)f2u(osa[wv][eg * 8 + j][px]);
                int gp = px0 + px;
                int prow = gp >> 8, pcol = gp & 255;
                *(short8*)(at2 + (((size_t)(bl * PW) + 1 + prow) * 16 + h * 4 + eg) * (PW * 8)
                           + (size_t)(1 + pcol) * 8) = o;
            }
        }
    }
}

// ---- conv2: implicit GEMM from subtiled at2 ----
__global__ __launch_bounds__(256, 3) void k_conv2(
    const unsigned short* __restrict__ at2, const short* __restrict__ w2t,
    const float* __restrict__ b2, float* __restrict__ out, int b0, int nb)
{
    const int bid = blockIdx.x;
    const int chunk = bid & 1;
    const int y   = (bid >> 1) & 255;
    const int bl  = bid >> 9;
    const int px0 = chunk * 128;
    const int bb  = b0 + bl;
    const int tx  = threadIdx.x;
    const int wv  = tx >> 6, l = tx & 63;
    const int lhi = l >> 4, llo = l & 15;

    __shared__ short xs[12 * 132 * 8];
    __shared__ float osf[32][132];

    float bias[2][4];
#pragma unroll
    for (int m = 0; m < 2; m++)
#pragma unroll
        for (int r = 0; r < 4; r++)
            bias[m][r] = b2[m * 16 + lhi * 4 + r];

    f32x4 acc[2][2];
#pragma unroll
    for (int t = 0; t < 2; t++)
#pragma unroll
        for (int m = 0; m < 2; m++) acc[t][m] = (f32x4){0.f, 0.f, 0.f, 0.f};

    for (int cc = 0; cc < 4; cc++) {
        __syncthreads();
#pragma unroll
        for (int i = 0; i < 3; i++) {
            int p = wv * 3 + i;
            int r = p >> 2, ch = p & 3;
            const char* src = (const char*)at2 +
                (((size_t)(bl * PW) + y + r) * 16 + cc * 4 + ch) * (PW * 16)
                + (size_t)px0 * 16 + (size_t)l * 16;
            char* dst = (char*)xs + p * 2112;
            gload16(src, dst);
            gload16(src + 1024, dst + 1024);
            if (l < 2) gload16(src + 2048, dst + 2048);
        }
        __syncthreads();

        short8 a[2], an[2];
#pragma unroll
        for (int m = 0; m < 2; m++)
            an[m] = *(const short8*)(w2t + ((size_t)(cc * 4 + lhi) * 32 + m * 16 + llo) * 8);
#pragma unroll
        for (int tap = 0; tap < 9; tap++) {
            const int dy = tap / 3, dx = tap % 3;
#pragma unroll
            for (int m = 0; m < 2; m++) a[m] = an[m];
            if (tap < 8) {
#pragma unroll
                for (int m = 0; m < 2; m++)
                    an[m] = *(const short8*)(w2t +
                        ((size_t)((tap + 1) * 16 + cc * 4 + lhi) * 32 + m * 16 + llo) * 8);
            }
#pragma unroll
            for (int t = 0; t < 2; t++) {
                short8 bfr = *(const short8*)&xs[(((dy * 4 + lhi) * 132) + (wv * 32 + t * 16 + llo + dx)) * 8];
#pragma unroll
                for (int m = 0; m < 2; m++)
                    acc[t][m] = __builtin_amdgcn_mfma_f32_16x16x32_bf16(a[m], bfr, acc[t][m], 0, 0, 0);
            }
        }
    }

#pragma unroll
    for (int t = 0; t < 2; t++)
#pragma unroll
        for (int m = 0; m < 2; m++)
#pragma unroll
            for (int r = 0; r < 4; r++)
                osf[m * 16 + lhi * 4 + r][wv * 32 + t * 16 + llo] = acc[t][m][r] + bias[m][r];
    __syncthreads();
#pragma unroll
    for (int p = 0; p < 4; p++) {
        int chl = p * 8 + (tx >> 5);
        float4 v = *(const float4*)&osf[chl][(tx & 31) * 4];
        *(float4*)(out + ((size_t)bb * COUT + chl) * NPIX + y * WW + px0 + (tx & 31) * 4) = v;
    }
}

extern "C" void kernel_launch(void* const* d_in, const int* in_sizes, int n_in,
                              void* d_out, int out_size, void* d_ws, size_t ws_size,
                              hipStream_t stream) {
    const float* x  = (const float*)d_in[0];
    const float* w1 = (const float*)d_in[1];
    const float* b1 = (const float*)d_in[2];
    const float* w2 = (const float*)d_in[3];
    const float* b2 = (const float*)d_in[4];
    float* out = (float*)d_out;

    char* ws = (char*)d_ws;
    float* wts  = (float*)(ws + 4096);
    short* w1t  = (short*)(ws + 69632);
    short* w2t  = (short*)(ws + 290816);
    const size_t OFF_XT = 1048576;

    int nb = 4;
    size_t xt_sz = (size_t)nb * PW * 4 * PW * 16;
    size_t pw_sz = (size_t)nb * 512 * 4096 * 4;
    size_t ps_sz = (size_t)nb * 512 * 128 * 4;
    size_t vt_sz = (size_t)nb * 2 * NPIX * 64 * 2;
    size_t at_sz = (size_t)nb * PW * PW * 256;
    if (ws_size < OFF_XT + xt_sz + pw_sz + ps_sz + vt_sz + at_sz) {
        nb = 1;
        xt_sz = (size_t)nb * PW * 4 * PW * 16;
        pw_sz = (size_t)nb * 512 * 4096 * 4;
        ps_sz = (size_t)nb * 512 * 128 * 4;
        vt_sz = (size_t)nb * 2 * NPIX * 64 * 2;
        at_sz = (size_t)nb * PW * PW * 256;
    }
    const size_t pw_off = OFF_XT + xt_sz;
    const size_t ps_off = pw_off + pw_sz;
    const size_t vt_off = ps_off + ps_sz;
    const size_t at_off = vt_off + vt_sz;

    unsigned short* xt2 = (unsigned short*)(ws + OFF_XT);
    float*          pw  = (float*)(ws + pw_off);
    float*          psb = (float*)(ws + ps_off);
    unsigned short* vt  = (unsigned short*)(ws + vt_off);
    unsigned short* at2 = (unsigned short*)(ws + at_off);

    k_w1t<<<dim3(9), 256, 0, stream>>>(w1, w1t);
    k_w2t<<<dim3(9), 256, 0, stream>>>(w2, w2t);

    for (int b0 = 0; b0 < B_; b0 += nb) {
        k_xt2    <<<dim3(PW, nb),        256, 0, stream>>>(x, xt2, b0);
        k_conv1  <<<dim3(2 * HH * nb),   256, 0, stream>>>(xt2, w1t, b1, vt, pw, psb, nb);
        k_wred   <<<dim3(nb * 4, 4),     256, 0, stream>>>(pw, psb, wts, b0);
        k_bord   <<<dim3(PW, nb),        256, 0, stream>>>(at2);
        k_attnout<<<dim3(NPIX / 256, nb),256, 0, stream>>>(vt, wts, at2, b0, nb);
        k_conv2  <<<dim3(2 * HH * nb),   256, 0, stream>>>(at2, w2t, b2, out, b0, nb);
    }
}

// Round 14
// 197.030 us; speedup vs baseline: 1.2199x; 1.1306x over previous
//
#include <hip/hip_runtime.h>
#include <hip/hip_bf16.h>

typedef __hip_bfloat16 bf16;
typedef __attribute__((ext_vector_type(8))) short short8;
typedef __attribute__((ext_vector_type(4))) float f32x4;
typedef __attribute__((ext_vector_type(16))) float f32x16;

#define B_    4
#define CIN   32
#define HH    256
#define WW    256
#define C1    384
#define NPIX  65536
#define CMID  128
#define COUT  32
#define PW    258

static __device__ __forceinline__ float u2f(unsigned short u) {
    unsigned int x = ((unsigned int)u) << 16;
    return __uint_as_float(x);
}
static __device__ __forceinline__ unsigned short f2u(float f) {
    bf16 h = __float2bfloat16(f);
    return __builtin_bit_cast(unsigned short, h);
}
static __device__ __forceinline__ unsigned int pk2(float lo, float hi) {
    return (unsigned int)f2u(lo) | ((unsigned int)f2u(hi) << 16);
}
static __device__ __forceinline__ void gload16(const void* src, void* dst) {
    __builtin_amdgcn_global_load_lds(
        (const __attribute__((address_space(1))) void*)src,
        (__attribute__((address_space(3))) void*)dst, 16, 0, 0);
}

// ---- w1(384,32,3,3) fp32 -> w1t[tap][cihi4][co384][8] bf16 ----
__global__ __launch_bounds__(256) void k_w1t(const float* __restrict__ w1, short* __restrict__ w1t) {
    const int tap = blockIdx.x;
    for (int i = threadIdx.x; i < 384 * 32; i += 256) {
        int co = i >> 5, cij = i & 31;
        w1t[((size_t)(tap * 4 + (cij >> 3)) * 384 + co) * 8 + (cij & 7)] =
            (short)f2u(w1[(size_t)i * 9 + tap]);
    }
}
// ---- w2(32,128,3,3) fp32 -> w2t[tap][cihi16][co32][8] bf16 ----
__global__ __launch_bounds__(256) void k_w2t(const float* __restrict__ w2, short* __restrict__ w2t) {
    const int tap = blockIdx.x;
    for (int i = threadIdx.x; i < 32 * 128; i += 256) {
        int co = i >> 7, cij = i & 127;
        w2t[((size_t)(tap * 16 + (cij >> 3)) * 32 + co) * 8 + (cij & 7)] =
            (short)f2u(w2[(size_t)i * 9 + tap]);
    }
}

// ---- x -> xt2[bl][row][cihi4][col PW][8ch] bf16, zero-padded ----
__global__ __launch_bounds__(256) void k_xt2(const float* __restrict__ x,
                                             unsigned short* __restrict__ xt2, int b0) {
    const int row = blockIdx.x, bl = blockIdx.y, b = b0 + bl;
    const int tx = threadIdx.x;
    unsigned short* rbase = xt2 + (size_t)(bl * PW + row) * 4 * PW * 8;
    const uint4 z = make_uint4(0u, 0u, 0u, 0u);
    if (row == 0 || row == PW - 1) {
        for (int i = tx; i < 4 * PW; i += 256) ((uint4*)rbase)[i] = z;
        return;
    }
    if (tx < 2) {
        int c = tx ? (PW - 1) : 0;
#pragma unroll
        for (int ch = 0; ch < 4; ch++)
            *(uint4*)(rbase + ((size_t)ch * PW + c) * 8) = z;
    }
    const int col = tx + 1;
    const size_t px = (size_t)(row - 1) * WW + tx;
    unsigned int pk[16];
#pragma unroll
    for (int c2 = 0; c2 < 16; c2++) {
        float v0 = x[((size_t)b * CIN + 2 * c2) * NPIX + px];
        float v1 = x[((size_t)b * CIN + 2 * c2 + 1) * NPIX + px];
        pk[c2] = pk2(v0, v1);
    }
#pragma unroll
    for (int ch = 0; ch < 4; ch++)
        *(uint4*)(rbase + ((size_t)ch * PW + col) * 8) =
            make_uint4(pk[ch * 4], pk[ch * 4 + 1], pk[ch * 4 + 2], pk[ch * 4 + 3]);
}

// ---- conv1 FUSED: qkv conv + attention-weights GEMM (unchanged from r13) ----
__global__ __launch_bounds__(256, 3) void k_conv1(
    const unsigned short* __restrict__ xt2, const short* __restrict__ w1t,
    const float* __restrict__ b1, unsigned short* __restrict__ vt,
    float* __restrict__ pw, float* __restrict__ ps, int nb)
{
    const int nblk = 512 * nb;
    const int m = ((int)blockIdx.x & 7) * (nblk >> 3) + ((int)blockIdx.x >> 3);
    const int chunk = m & 1;
    const int y   = (m >> 1) & 255;
    const int bl  = m >> 9;
    const int px0 = chunk * 128;
    const int cid = bl * 512 + y * 2 + chunk;
    const int tx  = threadIdx.x;
    const int wv  = tx >> 6, l = tx & 63;
    const int lhi = l >> 4, llo = l & 15;

    __shared__ short xs[12 * 132 * 8];
    __shared__ union {
        short os[64][136];
        short ost[128][66];
        float osw[4][32][32];
    } ou;

#pragma unroll
    for (int i = 0; i < 3; i++) {
        int p = wv * 3 + i;
        int r = p >> 2, ch = p & 3;
        const char* src = (const char*)xt2 +
            (((size_t)(bl * PW) + y + r) * 4 + ch) * (PW * 16) + (size_t)px0 * 16 + (size_t)l * 16;
        char* dst = (char*)xs + p * 2112;
        gload16(src, dst);
        gload16(src + 1024, dst + 1024);
        if (l < 2) gload16(src + 2048, dst + 2048);
    }
    __syncthreads();

    const short* wbase = w1t + ((size_t)lhi * 384 + llo) * 8;

    short8 qa[2][4];
    f32x4 wacc[2][2];
#pragma unroll
    for (int dt = 0; dt < 2; dt++)
#pragma unroll
        for (int et = 0; et < 2; et++) wacc[dt][et] = (f32x4){0.f, 0.f, 0.f, 0.f};
    float se0 = 0.f, se1 = 0.f;

#pragma unroll
    for (int cog = 0; cog < 6; cog++) {
        const int co0 = cog * 64;

        f32x4 acc[2][4];
#pragma unroll
        for (int t = 0; t < 2; t++)
#pragma unroll
            for (int mc = 0; mc < 4; mc++) acc[t][mc] = (f32x4){0.f, 0.f, 0.f, 0.f};

        short8 a[4], an[4];
#pragma unroll
        for (int mc = 0; mc < 4; mc++)
            an[mc] = *(const short8*)(wbase + ((size_t)co0 + mc * 16) * 8);
#pragma unroll
        for (int tap = 0; tap < 9; tap++) {
            const int dy = tap / 3, dx = tap % 3;
#pragma unroll
            for (int mc = 0; mc < 4; mc++) a[mc] = an[mc];
            if (tap < 8) {
#pragma unroll
                for (int mc = 0; mc < 4; mc++)
                    an[mc] = *(const short8*)(wbase +
                        ((size_t)(tap + 1) * 4 * 384 + co0 + mc * 16) * 8);
            }
#pragma unroll
            for (int t = 0; t < 2; t++) {
                short8 bfr = *(const short8*)&xs[(((dy * 4 + lhi) * 132) + (wv * 32 + t * 16 + llo + dx)) * 8];
#pragma unroll
                for (int mc = 0; mc < 4; mc++)
                    acc[t][mc] = __builtin_amdgcn_mfma_f32_16x16x32_bf16(a[mc], bfr, acc[t][mc], 0, 0, 0);
            }
        }

        float bias[4][4];
#pragma unroll
        for (int mc = 0; mc < 4; mc++)
#pragma unroll
            for (int r = 0; r < 4; r++)
                bias[mc][r] = b1[co0 + mc * 16 + lhi * 4 + r];

        __syncthreads();

        if (cog < 4) {
#pragma unroll
            for (int t = 0; t < 2; t++)
#pragma unroll
                for (int mc = 0; mc < 4; mc++)
#pragma unroll
                    for (int r = 0; r < 4; r++)
                        ou.os[mc * 16 + lhi * 4 + r][wv * 32 + t * 16 + llo] =
                            (short)f2u(acc[t][mc][r] + bias[mc][r]);
        } else {
#pragma unroll
            for (int t = 0; t < 2; t++)
#pragma unroll
                for (int mc = 0; mc < 4; mc++)
#pragma unroll
                    for (int r = 0; r < 4; r++)
                        ou.ost[wv * 32 + t * 16 + llo][mc * 16 + lhi * 4 + r] =
                            (short)f2u(acc[t][mc][r] + bias[mc][r]);
        }
        __syncthreads();

        if (cog < 2) {
            if ((wv >> 1) == cog) {
                const int chb = (wv & 1) * 32;
#pragma unroll
                for (int dt = 0; dt < 2; dt++)
#pragma unroll
                    for (int ks = 0; ks < 4; ks++)
                        qa[dt][ks] = *(const short8*)&ou.os[chb + dt * 16 + llo][ks * 32 + lhi * 8];
            }
        } else if (cog < 4) {
            if ((wv >> 1) == cog - 2) {
                const int chb = (wv & 1) * 32;
#pragma unroll
                for (int et = 0; et < 2; et++)
#pragma unroll
                    for (int ks = 0; ks < 4; ks++) {
                        short8 kf = *(const short8*)&ou.os[chb + et * 16 + llo][ks * 32 + lhi * 8];
                        short8 pf;
#pragma unroll
                        for (int j = 0; j < 8; j++) {
                            float ef = __expf(u2f((unsigned short)kf[j]));
                            if (et == 0) se0 += ef; else se1 += ef;
                            pf[j] = (short)f2u(ef);
                        }
#pragma unroll
                        for (int dt = 0; dt < 2; dt++)
                            wacc[dt][et] = __builtin_amdgcn_mfma_f32_16x16x32_bf16(
                                qa[dt][ks], pf, wacc[dt][et], 0, 0, 0);
                    }
            }
        } else {
            unsigned short* dst = vt + ((size_t)(bl * 2 + (cog - 4)) * NPIX
                                        + y * WW + px0) * 64;
#pragma unroll
            for (int i = 0; i < 4; i++) {
                int u = i * 256 + tx;
                int px = u >> 3, q = u & 7;
                uint4 v = *(const uint4*)&ou.ost[px][q * 8];
                *(uint4*)(dst + (size_t)u * 8) = v;
            }
        }
    }

    se0 += __shfl_xor(se0, 16); se0 += __shfl_xor(se0, 32);
    se1 += __shfl_xor(se1, 16); se1 += __shfl_xor(se1, 32);
    if (l < 16) {
        ps[(size_t)cid * 128 + wv * 32 + llo]      = se0;
        ps[(size_t)cid * 128 + wv * 32 + 16 + llo] = se1;
    }

    __syncthreads();
#pragma unroll
    for (int dt = 0; dt < 2; dt++)
#pragma unroll
        for (int et = 0; et < 2; et++)
#pragma unroll
            for (int r = 0; r < 4; r++)
                ou.osw[wv][dt * 16 + lhi * 4 + r][et * 16 + llo] = wacc[dt][et][r];
    __syncthreads();

    {
        float* pwp = pw + (size_t)cid * 4096;
        const float* osf = (const float*)&ou;
#pragma unroll
        for (int p = 0; p < 4; p++)
            *(float4*)(pwp + p * 1024 + tx * 4) = *(const float4*)(osf + p * 1024 + tx * 4);
    }
}

// ---- reduce partials over 512 chunks ----
__global__ __launch_bounds__(256) void k_wred(
    const float* __restrict__ pw, const float* __restrict__ ps,
    float* __restrict__ wts, int b0)
{
    const int bh = blockIdx.x;
    const int jq = blockIdx.y;
    const int bl = bh >> 2, h = bh & 3;
    const int tx = threadIdx.x;
    __shared__ float rinvs[32];
    if (tx < 32) {
        float s = 0.f;
        const float* pp = ps + (size_t)bl * 512 * 128 + h * 32 + tx;
        for (int c = 0; c < 512; c++) s += pp[(size_t)c * 128];
        rinvs[tx] = 1.f / s;
    }
    __syncthreads();
    const int i = jq * 256 + tx;
    const float* pwp = pw + (size_t)bl * 512 * 4096 + h * 1024 + i;
    float s = 0.f;
    for (int c = 0; c < 512; c++) s += pwp[(size_t)c * 4096];
    wts[(size_t)(b0 * 4 + bh) * 1024 + i] = s * rinvs[i & 31];
}

// ---- conv2 FUSED with attnout: a2 input tiles computed from vt via MFMA ----
// grid 2*HH*nb, XCD-swizzled. LDS: xs 26304 + osf 16896 + wtsb 8192 = 51392 -> 3 blk/CU
__global__ __launch_bounds__(256, 3) void k_conv2f(
    const unsigned short* __restrict__ vt, const short* __restrict__ w2t,
    const float* __restrict__ wts, const float* __restrict__ b2,
    float* __restrict__ out, int b0, int nb)
{
    const int nblk = 512 * nb;
    const int m = ((int)blockIdx.x & 7) * (nblk >> 3) + ((int)blockIdx.x >> 3);
    const int chunk = m & 1;
    const int y   = (m >> 1) & 255;
    const int bl  = m >> 9;
    const int px0 = chunk * 128;
    const int bb  = b0 + bl;
    const int tx  = threadIdx.x;
    const int wv  = tx >> 6, l = tx & 63;
    const int lhi = l >> 4, llo = l & 15;

    __shared__ short xs[12 * 137 * 8];        // [r*4+g][col137][8ch] a2 tile (stride-137 spreads banks)
    __shared__ float osf[32][132];
    __shared__ short wtsb[4][2][64][8];       // W bf16 B-frags per head/khalf

    // build wtsb from wts (fp32 -> bf16, MFMA B-frag order)
    for (int i = tx; i < 4096; i += 256) {
        int h = i >> 10, r = i & 1023;
        int kh = r >> 9, s = r & 511, li = s >> 3, j = s & 7;
        int d = kh * 16 + (li >> 5) * 8 + j, e = li & 31;
        wtsb[h][kh][li][j] = (short)f2u(wts[(size_t)bb * 4096 + h * 1024 + d * 32 + e]);
    }

    float bias[2][4];
#pragma unroll
    for (int mm = 0; mm < 2; mm++)
#pragma unroll
        for (int r = 0; r < 4; r++)
            bias[mm][r] = b2[mm * 16 + lhi * 4 + r];

    f32x4 acc[2][2];
#pragma unroll
    for (int t = 0; t < 2; t++)
#pragma unroll
        for (int mm = 0; mm < 2; mm++) acc[t][mm] = (f32x4){0.f, 0.f, 0.f, 0.f};

    __syncthreads();   // wtsb ready

    const int kg = l >> 5;          // K-half lane group for a2 MFMA
    const int pxa = l & 31;         // A-row (px within tile)

    for (int cc = 0; cc < 4; cc++) {
        // ---- build a2[3 rows][131 cols][32 ch of head cc] into xs via MFMA ----
        const int plane = cc >> 1, chofs = (cc & 1) * 32;
        short8 B0 = *(const short8*)&wtsb[cc][0][l][0];
        short8 B1 = *(const short8*)&wtsb[cc][1][l][0];

        for (int idx = wv; idx < 15; idx += 4) {
            int rr = idx / 5, ti = idx % 5;
            int ar = y - 1 + rr;
            int colbase = (ti < 4) ? ti * 32 : 99;
            if (ar < 0 || ar > 255) {
#pragma unroll
                for (int r = 0; r < 16; r++) {
                    int pxl = (r & 3) + 8 * (r >> 2) + 4 * kg;
                    int e = pxa;
                    xs[(((rr * 4 + (e >> 3)) * 137) + colbase + pxl) * 8 + (e & 7)] = 0;
                }
            } else {
                int ac = px0 - 1 + colbase + pxa;
                short8 A0 = (short8){0,0,0,0,0,0,0,0};
                short8 A1 = (short8){0,0,0,0,0,0,0,0};
                if (ac >= 0 && ac < 256) {
                    const unsigned short* vp = vt +
                        ((size_t)(bl * 2 + plane) * NPIX + (size_t)ar * 256 + ac) * 64
                        + chofs + kg * 8;
                    A0 = *(const short8*)vp;
                    A1 = *(const short8*)(vp + 16);
                }
                f32x16 aa;
#pragma unroll
                for (int r = 0; r < 16; r++) aa[r] = 0.f;
                aa = __builtin_amdgcn_mfma_f32_32x32x16_bf16(A0, B0, aa, 0, 0, 0);
                aa = __builtin_amdgcn_mfma_f32_32x32x16_bf16(A1, B1, aa, 0, 0, 0);
#pragma unroll
                for (int r = 0; r < 16; r++) {
                    int pxl = (r & 3) + 8 * (r >> 2) + 4 * kg;
                    int e = pxa;
                    xs[(((rr * 4 + (e >> 3)) * 137) + colbase + pxl) * 8 + (e & 7)] =
                        (short)f2u(aa[r]);
                }
            }
        }
        __syncthreads();   // xs ready

        // ---- conv2 tap loop for this ci-chunk (32 ch) ----
        short8 a[2], an[2];
#pragma unroll
        for (int mm = 0; mm < 2; mm++)
            an[mm] = *(const short8*)(w2t + ((size_t)(cc * 4 + lhi) * 32 + mm * 16 + llo) * 8);
#pragma unroll
        for (int tap = 0; tap < 9; tap++) {
            const int dy = tap / 3, dx = tap % 3;
#pragma unroll
            for (int mm = 0; mm < 2; mm++) a[mm] = an[mm];
            if (tap < 8) {
#pragma unroll
                for (int mm = 0; mm < 2; mm++)
                    an[mm] = *(const short8*)(w2t +
                        ((size_t)((tap + 1) * 16 + cc * 4 + lhi) * 32 + mm * 16 + llo) * 8);
            }
#pragma unroll
            for (int t = 0; t < 2; t++) {
                short8 bfr = *(const short8*)&xs[(((dy * 4 + lhi) * 137) + (wv * 32 + t * 16 + llo + dx)) * 8];
#pragma unroll
                for (int mm = 0; mm < 2; mm++)
                    acc[t][mm] = __builtin_amdgcn_mfma_f32_16x16x32_bf16(a[mm], bfr, acc[t][mm], 0, 0, 0);
            }
        }
        __syncthreads();   // xs reads done before next cc overwrites
    }

    // ---- epilogue (unchanged) ----
#pragma unroll
    for (int t = 0; t < 2; t++)
#pragma unroll
        for (int mm = 0; mm < 2; mm++)
#pragma unroll
            for (int r = 0; r < 4; r++)
                osf[mm * 16 + lhi * 4 + r][wv * 32 + t * 16 + llo] = acc[t][mm][r] + bias[mm][r];
    __syncthreads();
#pragma unroll
    for (int p = 0; p < 4; p++) {
        int chl = p * 8 + (tx >> 5);
        float4 v = *(const float4*)&osf[chl][(tx & 31) * 4];
        *(float4*)(out + ((size_t)bb * COUT + chl) * NPIX + y * WW + px0 + (tx & 31) * 4) = v;
    }
}

extern "C" void kernel_launch(void* const* d_in, const int* in_sizes, int n_in,
                              void* d_out, int out_size, void* d_ws, size_t ws_size,
                              hipStream_t stream) {
    const float* x  = (const float*)d_in[0];
    const float* w1 = (const float*)d_in[1];
    const float* b1 = (const float*)d_in[2];
    const float* w2 = (const float*)d_in[3];
    const float* b2 = (const float*)d_in[4];
    float* out = (float*)d_out;

    char* ws = (char*)d_ws;
    float* wts  = (float*)(ws + 4096);
    short* w1t  = (short*)(ws + 69632);
    short* w2t  = (short*)(ws + 290816);
    const size_t OFF_XT = 1048576;

    int nb = 4;
    size_t xt_sz = (size_t)nb * PW * 4 * PW * 16;
    size_t pw_sz = (size_t)nb * 512 * 4096 * 4;
    size_t ps_sz = (size_t)nb * 512 * 128 * 4;
    size_t vt_sz = (size_t)nb * 2 * NPIX * 64 * 2;
    if (ws_size < OFF_XT + xt_sz + pw_sz + ps_sz + vt_sz) {
        nb = 1;
        xt_sz = (size_t)nb * PW * 4 * PW * 16;
        pw_sz = (size_t)nb * 512 * 4096 * 4;
        ps_sz = (size_t)nb * 512 * 128 * 4;
        vt_sz = (size_t)nb * 2 * NPIX * 64 * 2;
    }
    const size_t pw_off = OFF_XT + xt_sz;
    const size_t ps_off = pw_off + pw_sz;
    const size_t vt_off = ps_off + ps_sz;

    unsigned short* xt2 = (unsigned short*)(ws + OFF_XT);
    float*          pw  = (float*)(ws + pw_off);
    float*          psb = (float*)(ws + ps_off);
    unsigned short* vt  = (unsigned short*)(ws + vt_off);

    k_w1t<<<dim3(9), 256, 0, stream>>>(w1, w1t);
    k_w2t<<<dim3(9), 256, 0, stream>>>(w2, w2t);

    for (int b0 = 0; b0 < B_; b0 += nb) {
        k_xt2  <<<dim3(PW, nb),      256, 0, stream>>>(x, xt2, b0);
        k_conv1<<<dim3(2 * HH * nb), 256, 0, stream>>>(xt2, w1t, b1, vt, pw, psb, nb);
        k_wred <<<dim3(nb * 4, 4),   256, 0, stream>>>(pw, psb, wts, b0);
        k_conv2f<<<dim3(2 * HH * nb),256, 0, stream>>>(vt, w2t, wts, b2, out, b0, nb);
    }
}